// Round 2
// baseline (92.095 us; speedup 1.0000x reference)
//
#include <hip/hip_runtime.h>
#include <math.h>

#define NPART 4096
#define NBLK  512
#define NTHR  256
#define IPB   8     // particles (i) per block: 4 waves, 2 i's per wave
#define SMAX  256   // local collision-set cap (expected ~110; own i's pre-seeded)
#define PPT   (NPART / NTHR)   // 16 particles staged per thread

// Constants, rounded exactly as the reference's weak-typed doubles -> f32
constexpr float RORC   = (float)(2.5e-5 + 3.15e-6);    // RO + RC
constexpr float RORC2  = RORC * RORC;
constexpr float RRF    = 8e-6f;
constexpr float RR2    = RRF * RRF;
constexpr float TWORC  = (float)(2.0 * 3.15e-6);
constexpr float TWORC2 = TWORC * TWORC;
constexpr float C21RC  = (float)(2.1 * 3.15e-6);
constexpr float RCAND2 = 1.6e-9f;                      // (4e-5)^2 >= 3-hop chain span
constexpr float C_ROT  = (float)(0.2 * 25.0 * 0.0028);
constexpr float C_RN1  = (float)0.07483314773547883;
constexpr float C_SQDT = (float)0.4472135954999579;
constexpr float C_TRV  = (float)(0.2 * 5e-7);
constexpr float C_HALF = (float)0.7071067811865476;
constexpr float C_SQ2T = (float)1.6733200530681511e-07;
constexpr float EPSF   = 1e-14f;

// ---------------------------------------------------------------------------
// vs R1 (brute force, IPB=4, ori from global): discrimination round.
// (1) ori staged in LDS -> the sweep's divergent branch has NO global loads
//     (was: ori[j] global load + vmcnt drain inside the inner loop).
// (2) 2 i's per wave, NBLK 1024->512: halves per-block fixed costs,
//     redundant staging, and LDS read traffic per pair-test.
// Per-lane j visit order and all reduction/epilogue arithmetic preserved
// verbatim (absmax was 0.0 - keep bit-exactness).
// LDS ~70 KB -> 2 blocks/CU, 512 blocks = one full-chip generation.
// ---------------------------------------------------------------------------
__global__ __launch_bounds__(NTHR, 2) void fused_all(
        const float2* __restrict__ pos, const float2* __restrict__ ori,
        const float* __restrict__ Deltas, const float* __restrict__ rot_noise,
        const float2* __restrict__ trans_noise, float2* __restrict__ out) {
    __shared__ float4   posL4[NPART / 2];     // 32 KB all positions, orig order
    __shared__ float4   oriL4[NPART / 2];     // 32 KB all orientations
    __shared__ float    sred[2 * NTHR];       // 2 KB mean tree
    __shared__ float    res[5][IPB];
    __shared__ unsigned bmap[NPART / 32];     // 512 B
    __shared__ int      Sidx[SMAX];           // 1 KB
    __shared__ float4   posS4[SMAX / 2];      // 2 KB
    __shared__ int      scnt;
    float2* posL = (float2*)posL4;
    float2* oriL = (float2*)oriL4;
    float2* posS = (float2*)posS4;

    const int tid  = threadIdx.x;
    const int il   = tid >> 6;            // wave 0..3
    const int lane = tid & 63;
    const int ia   = blockIdx.x * IPB + il;        // first own-i of this wave
    const int ib   = ia + 4;                       // second own-i

    if (tid == 0) scnt = IPB;             // slots 0..7 = own i's
    if (tid < IPB) Sidx[tid] = blockIdx.x * IPB + tid;
    if (tid < NPART / 32) bmap[tid] = 0u;

    // ---- stage positions + orientations -> LDS; mean partials ----
    float mx = 0.f, my = 0.f;
    #pragma unroll
    for (int k = 0; k < PPT; ++k) {
        const float2 v = pos[k * NTHR + tid];
        const float2 u = ori[k * NTHR + tid];
        posL[k * NTHR + tid] = v;
        oriL[k * NTHR + tid] = u;
        mx += v.x; my += v.y;
    }
    sred[tid] = mx; sred[NTHR + tid] = my;
    __syncthreads();                      // posL / oriL / sred / bmap ready

    // ---- A. brute-force sweep: one wave per TWO own-i, float4 = 2 j's ----
    const float2 pa = posL[ia];
    const float2 pb = posL[ib];
    float nrA = 0.f, sxA = 0.f, syA = 0.f, oxA = 0.f, oyA = 0.f;
    float nrB = 0.f, sxB = 0.f, syB = 0.f, oxB = 0.f, oyB = 0.f;
    #pragma unroll 2
    for (int t = lane; t < NPART / 2; t += 64) {
        const float4 w = posL4[t];
        // j0 = 2t (w.x,w.y), j1 = 2t+1 (w.z,w.w)
        const float dxa0 = w.x - pa.x, dya0 = w.y - pa.y;
        const float dxb0 = w.x - pb.x, dyb0 = w.y - pb.y;
        const float dxa1 = w.z - pa.x, dya1 = w.w - pa.y;
        const float dxb1 = w.z - pb.x, dyb1 = w.w - pb.y;
        const float r2a0 = fmaf(dxa0, dxa0, dya0 * dya0);
        const float r2b0 = fmaf(dxb0, dxb0, dyb0 * dyb0);
        const float r2a1 = fmaf(dxa1, dxa1, dya1 * dya1);
        const float r2b1 = fmaf(dxb1, dxb1, dyb1 * dyb1);

        if (r2a0 <= RCAND2 || r2b0 <= RCAND2) {   // candidate for either i
            const int j = 2 * t;
            atomicOr(&bmap[j >> 5], 1u << (j & 31));
        }
        if (r2a0 <= RORC2 || r2b0 <= RORC2) {     // inside_Ro for either i
            const float2 uj = oriL[2 * t];
            if (r2a0 <= RORC2) {
                oxA += uj.x; oyA += uj.y;
                if (r2a0 <= RR2 && r2a0 > 0.f) {
                    const float dt_ = fmaf(dxa0, uj.x, dya0 * uj.y);
                    const float cr_ = fmaf(dya0, uj.x, -dxa0 * uj.y);
                    if (!((dt_ <= 0.f) && (cr_ >= 0.f))) {
                        nrA += 1.f; sxA += w.x; syA += w.y;
                    }
                }
            }
            if (r2b0 <= RORC2) {
                oxB += uj.x; oyB += uj.y;
                if (r2b0 <= RR2 && r2b0 > 0.f) {
                    const float dt_ = fmaf(dxb0, uj.x, dyb0 * uj.y);
                    const float cr_ = fmaf(dyb0, uj.x, -dxb0 * uj.y);
                    if (!((dt_ <= 0.f) && (cr_ >= 0.f))) {
                        nrB += 1.f; sxB += w.x; syB += w.y;
                    }
                }
            }
        }
        if (r2a1 <= RCAND2 || r2b1 <= RCAND2) {
            const int j = 2 * t + 1;
            atomicOr(&bmap[j >> 5], 1u << (j & 31));
        }
        if (r2a1 <= RORC2 || r2b1 <= RORC2) {
            const float2 uj = oriL[2 * t + 1];
            if (r2a1 <= RORC2) {
                oxA += uj.x; oyA += uj.y;
                if (r2a1 <= RR2 && r2a1 > 0.f) {
                    const float dt_ = fmaf(dxa1, uj.x, dya1 * uj.y);
                    const float cr_ = fmaf(dya1, uj.x, -dxa1 * uj.y);
                    if (!((dt_ <= 0.f) && (cr_ >= 0.f))) {
                        nrA += 1.f; sxA += w.z; syA += w.w;
                    }
                }
            }
            if (r2b1 <= RORC2) {
                oxB += uj.x; oyB += uj.y;
                if (r2b1 <= RR2 && r2b1 > 0.f) {
                    const float dt_ = fmaf(dxb1, uj.x, dyb1 * uj.y);
                    const float cr_ = fmaf(dyb1, uj.x, -dxb1 * uj.y);
                    if (!((dt_ <= 0.f) && (cr_ >= 0.f))) {
                        nrB += 1.f; sxB += w.z; syB += w.w;
                    }
                }
            }
        }
    }
    {   // 64-lane shuffle reduction (whole wave; A -> slot il, B -> il+4)
        float vals[10] = {nrA, sxA, syA, oxA, oyA, nrB, sxB, syB, oxB, oyB};
        #pragma unroll
        for (int q = 0; q < 10; ++q)
            #pragma unroll
            for (int off = 32; off >= 1; off >>= 1)
                vals[q] += __shfl_down(vals[q], off);
        if (lane == 0) {
            res[0][il]     = vals[0]; res[1][il]     = vals[1];
            res[2][il]     = vals[2]; res[3][il]     = vals[3];
            res[4][il]     = vals[4];
            res[0][il + 4] = vals[5]; res[1][il + 4] = vals[6];
            res[2][il + 4] = vals[7]; res[3][il + 4] = vals[8];
            res[4][il + 4] = vals[9];
        }
    }
    __syncthreads();                      // bmap + res final

    // ---- B. S-compaction from bmap (own-block byte masked out) ----
    if (tid < NPART / 32) {
        unsigned bits = bmap[tid];
        if (tid == (int)(blockIdx.x >> 2))
            bits &= ~(0xFFu << ((blockIdx.x & 3) * 8));
        while (bits) {
            const int b = __ffs(bits) - 1;
            bits &= bits - 1;
            const int slot = atomicAdd(&scnt, 1);
            if (slot < SMAX) Sidx[slot] = tid * 32 + b;
        }
    }
    __syncthreads();
    const int nS = (scnt < SMAX) ? scnt : SMAX;

    // ---- D1. translate S members (reference-exact expression) ----
    if (tid < nS) {
        const int p = Sidx[tid];
        const float2 pq = posL[p];
        const float2 uu = oriL[p];
        const float2 tn = trans_noise[p];
        posS[tid] = make_float2(
            pq.x + (C_TRV * uu.x + ((tn.x * C_HALF) * C_SQ2T) * C_SQDT),
            pq.y + (C_TRV * uu.y + ((tn.y * C_HALF) * C_SQ2T) * C_SQDT));
    }

    // ---- C. mean of all positions (identical tree) ----
    for (int s = NTHR / 2; s > 0; s >>= 1) {
        if (tid < s) { sred[tid] += sred[tid + s]; sred[NTHR + tid] += sred[NTHR + tid + s]; }
        __syncthreads();
    }
    const float cmx = sred[0]    * (1.f / NPART);
    const float cmy = sred[NTHR] * (1.f / NPART);

    // ---- C2. per-i epilogue (8 threads; sections 1..4) ----
    if (tid < IPB) {
        const int g2 = blockIdx.x * IPB + tid;
        const float2 p = posL[g2];
        const float2 u = oriL[g2];
        const float nrv = res[0][tid], sxv = res[1][tid], syv = res[2][tid];
        const float osx = res[3][tid], osy = res[4][tid];

        const float inv = 1.f / fmaxf(nrv, 1.f);
        const float sg  = (nrv > 0.f) ? 1.f : 0.f;
        const float Sx = sxv * inv - p.x * sg;
        const float Sy = syv * inv - p.y * sg;
        const float dxv = -Sx, dyv = -Sy;        // d = -S

        const float Psx = cmx - p.x;
        const float Psy = cmy - p.y;

        float sd, cd;
        sincosf(Deltas[0], &sd, &cd);
        const float Lx = Psx * cd - Psy * sd;    // Ps * exp(+i*Delta)
        const float Ly = Psx * sd + Psy * cd;
        const float Rx = Psx * cd + Psy * sd;    // Ps * exp(-i*Delta)
        const float Ry = Psy * cd - Psx * sd;

        const float no  = fmaxf(sqrtf(osx * osx + osy * osy + 1e-30f), EPSF);
        const float nl  = fmaxf(sqrtf(Lx * Lx + Ly * Ly + 1e-30f), EPSF);
        const float nrr = fmaxf(sqrtf(Rx * Rx + Ry * Ry + 1e-30f), EPSF);
        const float csl = (Lx * osx + Ly * osy) / (nl * no);
        const float csr = (Rx * osx + Ry * osy) / (nrr * no);
        const bool left = (csl >= csr);
        const float bx = left ? Lx : Rx;
        const float by = left ? Ly : Ry;

        float cx, cy;
        if (dxv != 0.f || dyv != 0.f)    { cx = dxv; cy = dyv; }
        else if (bx != 0.f || by != 0.f) { cx = bx;  cy = by;  }
        else                             { cx = 1.f; cy = 0.f; }

        const float dt_ = cx * u.x + cy * u.y;
        const float cr_ = cy * u.x - cx * u.y;
        const float sin_t = cr_ / sqrtf(dt_ * dt_ + cr_ * cr_);

        const float ang = C_ROT * sin_t + (rot_noise[g2] * C_RN1) * C_SQDT;
        float sa, ca;
        sincosf(ang, &sa, &ca);
        out[1 * NPART + g2] = make_float2(u.x * ca - u.y * sa,
                                          u.x * sa + u.y * ca);
        out[2 * NPART + g2] = make_float2(osx, osy);
        out[3 * NPART + g2] = make_float2(Lx, Ly);
        out[4 * NPART + g2] = make_float2(Rx, Ry);
    }
    __syncthreads();                      // posS complete

    // ---- D2. three local JACOBI passes over S (nS <= 256 == NTHR) ----
    for (int pass = 0; pass < 3; ++pass) {
        float px = 0.f, py = 0.f, ax = 0.f, ay = 0.f;
        const bool mv = (tid < nS);
        if (mv) { px = posS[tid].x; py = posS[tid].y; }
        int b = 0;
        for (; b + 4 <= nS; b += 4) {
            const float4 w0 = posS4[(b >> 1)];
            const float4 w1 = posS4[(b >> 1) + 1];
            const float bxs[4] = {w0.x, w0.z, w1.x, w1.z};
            const float bys[4] = {w0.y, w0.w, w1.y, w1.w};
            #pragma unroll
            for (int s = 0; s < 4; ++s) {
                if (mv) {
                    const float dx = bxs[s] - px, dy = bys[s] - py;
                    const float r2 = fmaf(dx, dx, dy * dy);
                    if (r2 <= TWORC2 && r2 > 0.f) {
                        const float ab = sqrtf(r2);
                        const float sc = (C21RC - ab) * 0.5f / ab;
                        ax = fmaf(dx, sc, ax);
                        ay = fmaf(dy, sc, ay);
                    }
                }
            }
        }
        for (; b < nS; ++b) {
            const float2 pb2 = posS[b];
            if (mv) {
                const float dx = pb2.x - px, dy = pb2.y - py;
                const float r2 = fmaf(dx, dx, dy * dy);
                if (r2 <= TWORC2 && r2 > 0.f) {
                    const float ab = sqrtf(r2);
                    const float sc = (C21RC - ab) * 0.5f / ab;
                    ax = fmaf(dx, sc, ax);
                    ay = fmaf(dy, sc, ay);
                }
            }
        }
        __syncthreads();                  // all reads done (Jacobi)
        if (mv) posS[tid] = make_float2(px - ax, py - ay);
        __syncthreads();
    }
    // ---- section 0: own 8 i's are slots 0..7 of S ----
    if (tid < IPB)
        out[0 * NPART + blockIdx.x * IPB + tid] = posS[tid];
}

extern "C" void kernel_launch(void* const* d_in, const int* in_sizes, int n_in,
                              void* d_out, int out_size, void* d_ws, size_t ws_size,
                              hipStream_t stream) {
    const float2* pos = (const float2*)d_in[0];
    const float2* ori = (const float2*)d_in[1];
    const float*  del = (const float*)d_in[2];
    const float*  rn  = (const float*)d_in[3];
    const float2* tn  = (const float2*)d_in[4];
    float2* o2 = (float2*)d_out;          // [5][N] float2
    (void)d_ws; (void)ws_size;

    fused_all<<<dim3(NBLK), dim3(NTHR), 0, stream>>>(pos, ori, del, rn, tn, o2);
}

// Round 3
// 85.836 us; speedup vs baseline: 1.0729x; 1.0729x over previous
//
#include <hip/hip_runtime.h>
#include <math.h>

#define NPART 4096
#define NBLK  1024
#define NTHR  256
#define IPB   4     // particles (i) per block: one 64-lane wave per i
#define SMAX  256   // local collision-set cap (expected ~60; own i's pre-seeded)
#define PPT   (NPART / NTHR)   // 16 particles per thread in the mean pass

// Constants, rounded exactly as the reference's weak-typed doubles -> f32
constexpr float RORC   = (float)(2.5e-5 + 3.15e-6);    // RO + RC
constexpr float RORC2  = RORC * RORC;
constexpr float RRF    = 8e-6f;
constexpr float RR2    = RRF * RRF;
constexpr float TWORC  = (float)(2.0 * 3.15e-6);
constexpr float TWORC2 = TWORC * TWORC;
constexpr float C21RC  = (float)(2.1 * 3.15e-6);
constexpr float RCAND2 = 1.6e-9f;                      // (4e-5)^2 >= 3-hop chain span
constexpr float C_ROT  = (float)(0.2 * 25.0 * 0.0028);
constexpr float C_RN1  = (float)0.07483314773547883;
constexpr float C_SQDT = (float)0.4472135954999579;
constexpr float C_TRV  = (float)(0.2 * 5e-7);
constexpr float C_HALF = (float)0.7071067811865476;
constexpr float C_SQ2T = (float)1.6733200530681511e-07;
constexpr float EPSF   = 1e-14f;

// ---------------------------------------------------------------------------
// vs R1 (best, 82.9): occupancy round. R2 proved the kernel is latency-bound
// (halving blocks/CU regressed 9us at identical work). pos is 32 KB == L1
// size and the sweep reads it coalesced, so the LDS mirror is pure occupancy
// tax: drop posL4 entirely, read pos/ori straight from global (L1-resident).
// LDS 37.7 -> ~5.6 KB; __launch_bounds__(256,8) -> 8 blocks/CU = 32 waves/CU
// (2x R1's 16). All arithmetic, visit order, and phase order preserved
// verbatim from R1 (absmax 0.0) - replaced reads are bit-identical values.
// ---------------------------------------------------------------------------
__global__ __launch_bounds__(NTHR, 8) void fused_all(
        const float2* __restrict__ pos, const float2* __restrict__ ori,
        const float* __restrict__ Deltas, const float* __restrict__ rot_noise,
        const float2* __restrict__ trans_noise, float2* __restrict__ out) {
    __shared__ float    sred[2 * NTHR];       // 2 KB mean tree
    __shared__ float    res[5][IPB];
    __shared__ unsigned bmap[NPART / 32];     // 512 B
    __shared__ int      Sidx[SMAX];           // 1 KB
    __shared__ float4   posS4[SMAX / 2];      // 2 KB
    __shared__ int      scnt;
    float2* posS = (float2*)posS4;
    const float4* __restrict__ pos4 = (const float4*)pos;

    const int tid  = threadIdx.x;
    const int il   = tid >> 6;            // own-i 0..3 (one wave each)
    const int lane = tid & 63;
    const int gi   = blockIdx.x * IPB + il;

    if (tid == 0) scnt = IPB;             // slots 0..3 = own i's
    if (tid < IPB) Sidx[tid] = blockIdx.x * IPB + tid;
    if (tid < NPART / 32) bmap[tid] = 0u;

    // ---- mean partials (same per-thread k*NTHR+tid mapping and order);
    //      these coalesced loads also warm L1 for the sweep ----
    float mx = 0.f, my = 0.f;
    #pragma unroll
    for (int k = 0; k < PPT; ++k) {
        const float2 v = pos[k * NTHR + tid];
        mx += v.x; my += v.y;
    }
    sred[tid] = mx; sred[NTHR + tid] = my;
    __syncthreads();                      // sred / bmap / Sidx ready

    // ---- A. brute-force sweep: one wave per own-i, float4 = 2 j's,
    //      straight from global (L1-resident, lane-coalesced) ----
    const float2 pi = pos[gi];
    float nr = 0.f, sx = 0.f, sy = 0.f, oxs = 0.f, oys = 0.f;
    #pragma unroll 2
    for (int t = lane; t < NPART / 2; t += 64) {
        const float4 w = pos4[t];
        const float dx0 = w.x - pi.x, dy0 = w.y - pi.y;
        const float r20 = fmaf(dx0, dx0, dy0 * dy0);
        const float dx1 = w.z - pi.x, dy1 = w.w - pi.y;
        const float r21 = fmaf(dx1, dx1, dy1 * dy1);
        if (r20 <= RCAND2) {              // candidate (incl. self; masked in B)
            const int j = 2 * t;
            atomicOr(&bmap[j >> 5], 1u << (j & 31));
            if (r20 <= RORC2) {           // inside_Ro
                const float2 uj = ori[j];
                oxs += uj.x; oys += uj.y;
                if (r20 <= RR2 && r20 > 0.f) {
                    // in_front fails <=> dot<=0 && cross>=0
                    const float dt_ = fmaf(dx0, uj.x, dy0 * uj.y);
                    const float cr_ = fmaf(dy0, uj.x, -dx0 * uj.y);
                    if (!((dt_ <= 0.f) && (cr_ >= 0.f))) {
                        nr += 1.f; sx += w.x; sy += w.y;
                    }
                }
            }
        }
        if (r21 <= RCAND2) {
            const int j = 2 * t + 1;
            atomicOr(&bmap[j >> 5], 1u << (j & 31));
            if (r21 <= RORC2) {
                const float2 uj = ori[j];
                oxs += uj.x; oys += uj.y;
                if (r21 <= RR2 && r21 > 0.f) {
                    const float dt_ = fmaf(dx1, uj.x, dy1 * uj.y);
                    const float cr_ = fmaf(dy1, uj.x, -dx1 * uj.y);
                    if (!((dt_ <= 0.f) && (cr_ >= 0.f))) {
                        nr += 1.f; sx += w.z; sy += w.w;
                    }
                }
            }
        }
    }
    {   // 64-lane shuffle reduction (whole wave belongs to one i)
        float vals[5] = {nr, sx, sy, oxs, oys};
        #pragma unroll
        for (int q = 0; q < 5; ++q)
            #pragma unroll
            for (int off = 32; off >= 1; off >>= 1)
                vals[q] += __shfl_down(vals[q], off);
        if (lane == 0) {
            res[0][il] = vals[0]; res[1][il] = vals[1]; res[2][il] = vals[2];
            res[3][il] = vals[3]; res[4][il] = vals[4];
        }
    }
    __syncthreads();                      // bmap + res final

    // ---- B. S-compaction from bmap (own-block nibble masked out) ----
    if (tid < NPART / 32) {
        unsigned bits = bmap[tid];
        if (tid == (int)(blockIdx.x >> 3))
            bits &= ~(0xFu << ((blockIdx.x & 7) * 4));
        while (bits) {
            const int b = __ffs(bits) - 1;
            bits &= bits - 1;
            const int slot = atomicAdd(&scnt, 1);
            if (slot < SMAX) Sidx[slot] = tid * 32 + b;
        }
    }
    __syncthreads();
    const int nS = (scnt < SMAX) ? scnt : SMAX;

    // ---- D1. translate S members (reference-exact expression) ----
    if (tid < nS) {
        const int p = Sidx[tid];
        const float2 pq = pos[p];
        const float2 uu = ori[p];
        const float2 tn = trans_noise[p];
        posS[tid] = make_float2(
            pq.x + (C_TRV * uu.x + ((tn.x * C_HALF) * C_SQ2T) * C_SQDT),
            pq.y + (C_TRV * uu.y + ((tn.y * C_HALF) * C_SQ2T) * C_SQDT));
    }

    // ---- C. mean of all positions (identical tree) ----
    for (int s = NTHR / 2; s > 0; s >>= 1) {
        if (tid < s) { sred[tid] += sred[tid + s]; sred[NTHR + tid] += sred[NTHR + tid + s]; }
        __syncthreads();
    }
    const float cmx = sred[0]    * (1.f / NPART);
    const float cmy = sred[NTHR] * (1.f / NPART);

    // ---- C2. per-i epilogue (4 threads; sections 1..4) ----
    if (tid < IPB) {
        const int g2 = blockIdx.x * IPB + tid;
        const float2 p = pos[g2];
        const float2 u = ori[g2];
        const float nrv = res[0][tid], sxv = res[1][tid], syv = res[2][tid];
        const float osx = res[3][tid], osy = res[4][tid];

        const float inv = 1.f / fmaxf(nrv, 1.f);
        const float sg  = (nrv > 0.f) ? 1.f : 0.f;
        const float Sx = sxv * inv - p.x * sg;
        const float Sy = syv * inv - p.y * sg;
        const float dxv = -Sx, dyv = -Sy;        // d = -S

        const float Psx = cmx - p.x;
        const float Psy = cmy - p.y;

        float sd, cd;
        sincosf(Deltas[0], &sd, &cd);
        const float Lx = Psx * cd - Psy * sd;    // Ps * exp(+i*Delta)
        const float Ly = Psx * sd + Psy * cd;
        const float Rx = Psx * cd + Psy * sd;    // Ps * exp(-i*Delta)
        const float Ry = Psy * cd - Psx * sd;

        const float no  = fmaxf(sqrtf(osx * osx + osy * osy + 1e-30f), EPSF);
        const float nl  = fmaxf(sqrtf(Lx * Lx + Ly * Ly + 1e-30f), EPSF);
        const float nrr = fmaxf(sqrtf(Rx * Rx + Ry * Ry + 1e-30f), EPSF);
        const float csl = (Lx * osx + Ly * osy) / (nl * no);
        const float csr = (Rx * osx + Ry * osy) / (nrr * no);
        const bool left = (csl >= csr);
        const float bx = left ? Lx : Rx;
        const float by = left ? Ly : Ry;

        float cx, cy;
        if (dxv != 0.f || dyv != 0.f)    { cx = dxv; cy = dyv; }
        else if (bx != 0.f || by != 0.f) { cx = bx;  cy = by;  }
        else                             { cx = 1.f; cy = 0.f; }

        const float dt_ = cx * u.x + cy * u.y;
        const float cr_ = cy * u.x - cx * u.y;
        const float sin_t = cr_ / sqrtf(dt_ * dt_ + cr_ * cr_);

        const float ang = C_ROT * sin_t + (rot_noise[g2] * C_RN1) * C_SQDT;
        float sa, ca;
        sincosf(ang, &sa, &ca);
        out[1 * NPART + g2] = make_float2(u.x * ca - u.y * sa,
                                          u.x * sa + u.y * ca);
        out[2 * NPART + g2] = make_float2(osx, osy);
        out[3 * NPART + g2] = make_float2(Lx, Ly);
        out[4 * NPART + g2] = make_float2(Rx, Ry);
    }
    __syncthreads();                      // posS complete

    // ---- D2. three local JACOBI passes over S (nS <= 256 == NTHR) ----
    for (int pass = 0; pass < 3; ++pass) {
        float px = 0.f, py = 0.f, ax = 0.f, ay = 0.f;
        const bool mv = (tid < nS);
        if (mv) { px = posS[tid].x; py = posS[tid].y; }
        int b = 0;
        for (; b + 4 <= nS; b += 4) {
            const float4 w0 = posS4[(b >> 1)];
            const float4 w1 = posS4[(b >> 1) + 1];
            const float bxs[4] = {w0.x, w0.z, w1.x, w1.z};
            const float bys[4] = {w0.y, w0.w, w1.y, w1.w};
            #pragma unroll
            for (int s = 0; s < 4; ++s) {
                if (mv) {
                    const float dx = bxs[s] - px, dy = bys[s] - py;
                    const float r2 = fmaf(dx, dx, dy * dy);
                    if (r2 <= TWORC2 && r2 > 0.f) {
                        const float ab = sqrtf(r2);
                        const float sc = (C21RC - ab) * 0.5f / ab;
                        ax = fmaf(dx, sc, ax);
                        ay = fmaf(dy, sc, ay);
                    }
                }
            }
        }
        for (; b < nS; ++b) {
            const float2 pb = posS[b];
            if (mv) {
                const float dx = pb.x - px, dy = pb.y - py;
                const float r2 = fmaf(dx, dx, dy * dy);
                if (r2 <= TWORC2 && r2 > 0.f) {
                    const float ab = sqrtf(r2);
                    const float sc = (C21RC - ab) * 0.5f / ab;
                    ax = fmaf(dx, sc, ax);
                    ay = fmaf(dy, sc, ay);
                }
            }
        }
        __syncthreads();                  // all reads done (Jacobi)
        if (mv) posS[tid] = make_float2(px - ax, py - ay);
        __syncthreads();
    }
    // ---- section 0: own 4 i's are slots 0..3 of S ----
    if (tid < IPB)
        out[0 * NPART + blockIdx.x * IPB + tid] = posS[tid];
}

extern "C" void kernel_launch(void* const* d_in, const int* in_sizes, int n_in,
                              void* d_out, int out_size, void* d_ws, size_t ws_size,
                              hipStream_t stream) {
    const float2* pos = (const float2*)d_in[0];
    const float2* ori = (const float2*)d_in[1];
    const float*  del = (const float*)d_in[2];
    const float*  rn  = (const float*)d_in[3];
    const float2* tn  = (const float2*)d_in[4];
    float2* o2 = (float2*)d_out;          // [5][N] float2
    (void)d_ws; (void)ws_size;

    fused_all<<<dim3(NBLK), dim3(NTHR), 0, stream>>>(pos, ori, del, rn, tn, o2);
}

// Round 4
// 84.554 us; speedup vs baseline: 1.0892x; 1.0152x over previous
//
#include <hip/hip_runtime.h>
#include <math.h>

#define NPART 4096
#define NBLK  1024
#define NTHR  256
#define IPB   4     // particles (i) per block: one 64-lane wave per i
#define SMAX  256   // local collision-set cap (expected ~60; own i's pre-seeded)
#define PPT   (NPART / NTHR)   // 16 particles per thread in the mean pass

// Constants, rounded exactly as the reference's weak-typed doubles -> f32
constexpr float RORC   = (float)(2.5e-5 + 3.15e-6);    // RO + RC
constexpr float RORC2  = RORC * RORC;
constexpr float RRF    = 8e-6f;
constexpr float RR2    = RRF * RRF;
constexpr float TWORC  = (float)(2.0 * 3.15e-6);
constexpr float TWORC2 = TWORC * TWORC;
constexpr float C21RC  = (float)(2.1 * 3.15e-6);
constexpr float RCAND2 = 1.6e-9f;                      // (4e-5)^2 >= 3-hop chain span
constexpr float C_ROT  = (float)(0.2 * 25.0 * 0.0028);
constexpr float C_RN1  = (float)0.07483314773547883;
constexpr float C_SQDT = (float)0.4472135954999579;
constexpr float C_TRV  = (float)(0.2 * 5e-7);
constexpr float C_HALF = (float)0.7071067811865476;
constexpr float C_SQ2T = (float)1.6733200530681511e-07;
constexpr float EPSF   = 1e-14f;

// ---------------------------------------------------------------------------
// vs R3: latency-chain round. Model refit says kernel ~36-38us across R1-R3
// while VALU work is ~3us (R0 counters: VALUBusy 7.9%) -> serial stalls, not
// throughput. Changes (all FP orders bit-identical):
//  (a) launch_bounds(256,6): 85-VGPR cap. R3's (256,8)=64-VGPR cap likely
//      SPILLED the sweep loop (R0 needed 88) -- explains R3 == R1.
//  (b) all cold loads issued at kernel entry: pi, Deltas, rot_noise + one
//      cache-line-per-thread warm of ori/trans_noise (kept live via asm sink)
//      so mid-kernel dependent sections never see a 900cy HBM miss.
//  (c) sweep manually batched 4-deep: 4 float4 loads in flight per step
//      (same per-lane visit order -> bit-exact accumulators).
//  (d) mean pass moved after sweep (L1-hot); barriers fused 17 -> 10; mean
//      tree s<=32 via wave-0 shuffles with the identical pairwise tree.
// ---------------------------------------------------------------------------
__global__ __launch_bounds__(NTHR, 6) void fused_all(
        const float2* __restrict__ pos, const float2* __restrict__ ori,
        const float* __restrict__ Deltas, const float* __restrict__ rot_noise,
        const float2* __restrict__ trans_noise, float2* __restrict__ out) {
    __shared__ float    sred[2 * NTHR];       // 2 KB mean tree
    __shared__ float    res[5][IPB];
    __shared__ unsigned bmap[NPART / 32];     // 512 B
    __shared__ int      Sidx[SMAX];           // 1 KB
    __shared__ float4   posS4[SMAX / 2];      // 2 KB
    __shared__ int      scnt;
    float2* posS = (float2*)posS4;
    const float4* __restrict__ pos4 = (const float4*)pos;

    const int tid  = threadIdx.x;
    const int il   = tid >> 6;            // own-i 0..3 (one wave each)
    const int lane = tid & 63;
    const int gi   = blockIdx.x * IPB + il;

    // ---- entry: issue every cold load now, consume late ----
    const float2 pi   = pos[gi];                       // sweep anchor
    const float  delv = Deltas[0];                     // uniform scalar
    float rn_early = 0.f;
    if (tid < IPB) rn_early = rot_noise[blockIdx.x * IPB + tid];
    {   // warm ori + trans_noise into L1/L2: one 128B line per thread = 32KB each
        const float2 ow = ori[tid * PPT];
        const float2 tw = trans_noise[tid * PPT];
        asm volatile("" :: "v"(ow.x), "v"(tw.x));      // keep loads live (no DCE)
    }

    if (tid == 0) scnt = IPB;             // slots 0..3 = own i's
    if (tid < IPB) Sidx[tid] = blockIdx.x * IPB + tid;
    if (tid < NPART / 32) bmap[tid] = 0u;
    __syncthreads();                      // #1: bmap/scnt/Sidx visible

    // ---- A. brute-force sweep, 4 float4 loads in flight per step ----
    float nr = 0.f, sx = 0.f, sy = 0.f, oxs = 0.f, oys = 0.f;
    auto pair2 = [&](const float4& w, int jbase) {
        const float dx0 = w.x - pi.x, dy0 = w.y - pi.y;
        const float r20 = fmaf(dx0, dx0, dy0 * dy0);
        const float dx1 = w.z - pi.x, dy1 = w.w - pi.y;
        const float r21 = fmaf(dx1, dx1, dy1 * dy1);
        if (r20 <= RCAND2) {              // candidate (incl. self; masked in B)
            atomicOr(&bmap[jbase >> 5], 1u << (jbase & 31));
            if (r20 <= RORC2) {           // inside_Ro
                const float2 uj = ori[jbase];
                oxs += uj.x; oys += uj.y;
                if (r20 <= RR2 && r20 > 0.f) {
                    // in_front fails <=> dot<=0 && cross>=0
                    const float dt_ = fmaf(dx0, uj.x, dy0 * uj.y);
                    const float cr_ = fmaf(dy0, uj.x, -dx0 * uj.y);
                    if (!((dt_ <= 0.f) && (cr_ >= 0.f))) {
                        nr += 1.f; sx += w.x; sy += w.y;
                    }
                }
            }
        }
        if (r21 <= RCAND2) {
            const int j1 = jbase + 1;
            atomicOr(&bmap[j1 >> 5], 1u << (j1 & 31));
            if (r21 <= RORC2) {
                const float2 uj = ori[j1];
                oxs += uj.x; oys += uj.y;
                if (r21 <= RR2 && r21 > 0.f) {
                    const float dt_ = fmaf(dx1, uj.x, dy1 * uj.y);
                    const float cr_ = fmaf(dy1, uj.x, -dx1 * uj.y);
                    if (!((dt_ <= 0.f) && (cr_ >= 0.f))) {
                        nr += 1.f; sx += w.z; sy += w.w;
                    }
                }
            }
        }
    };
    // per-lane t sequence t0, t0+64, t0+128, t0+192, t0+256... == original
    // t=lane; t+=64 ascending order -> accumulation order bit-identical.
    for (int t0 = lane; t0 < NPART / 2; t0 += 256) {
        const float4 w0 = pos4[t0];
        const float4 w1 = pos4[t0 + 64];
        const float4 w2 = pos4[t0 + 128];
        const float4 w3 = pos4[t0 + 192];
        pair2(w0, 2 * t0);
        pair2(w1, 2 * (t0 + 64));
        pair2(w2, 2 * (t0 + 128));
        pair2(w3, 2 * (t0 + 192));
    }
    {   // 64-lane shuffle reduction (whole wave belongs to one i)
        float vals[5] = {nr, sx, sy, oxs, oys};
        #pragma unroll
        for (int q = 0; q < 5; ++q)
            #pragma unroll
            for (int off = 32; off >= 1; off >>= 1)
                vals[q] += __shfl_down(vals[q], off);
        if (lane == 0) {
            res[0][il] = vals[0]; res[1][il] = vals[1]; res[2][il] = vals[2];
            res[3][il] = vals[3]; res[4][il] = vals[4];
        }
    }

    // ---- mean pass (now L1-hot: sweep just streamed pos) ----
    float mx = 0.f, my = 0.f;
    #pragma unroll
    for (int k = 0; k < PPT; ++k) {
        const float2 v = pos[k * NTHR + tid];
        mx += v.x; my += v.y;
    }
    sred[tid] = mx; sred[NTHR + tid] = my;
    __syncthreads();                      // #2: bmap final, res final, sred written

    // ---- B. tree s=128 + S-compaction (both tid<128) ----
    if (tid < 128) {
        sred[tid]        += sred[tid + 128];
        sred[NTHR + tid] += sred[NTHR + tid + 128];
        unsigned bits = bmap[tid];
        if (tid == (int)(blockIdx.x >> 3))
            bits &= ~(0xFu << ((blockIdx.x & 7) * 4));
        while (bits) {
            const int b = __ffs(bits) - 1;
            bits &= bits - 1;
            const int slot = atomicAdd(&scnt, 1);
            if (slot < SMAX) Sidx[slot] = tid * 32 + b;
        }
    }
    __syncthreads();                      // #3: scnt/Sidx final; s=128 done
    const int nS = (scnt < SMAX) ? scnt : SMAX;

    // ---- tree s=64 + D1 translate (reference-exact expression) ----
    if (tid < 64) {
        sred[tid]        += sred[tid + 64];
        sred[NTHR + tid] += sred[NTHR + tid + 64];
    }
    if (tid < nS) {
        const int p = Sidx[tid];
        const float2 pq = pos[p];
        const float2 uu = ori[p];
        const float2 tn = trans_noise[p];
        posS[tid] = make_float2(
            pq.x + (C_TRV * uu.x + ((tn.x * C_HALF) * C_SQ2T) * C_SQDT),
            pq.y + (C_TRV * uu.y + ((tn.y * C_HALF) * C_SQ2T) * C_SQDT));
    }
    __syncthreads();                      // #4: s=64 done; posS complete

    // ---- tree s<=32 in wave 0 via shuffles (identical pairwise tree) ----
    float cmx = 0.f, cmy = 0.f;
    if (il == 0) {
        float vx = sred[lane];            // lane < 64
        float vy = sred[NTHR + lane];
        #pragma unroll
        for (int off = 32; off >= 1; off >>= 1) {
            vx += __shfl_down(vx, off);   // lane l pairs with l+off == ladder
            vy += __shfl_down(vy, off);
        }
        cmx = __shfl(vx, 0) * (1.f / NPART);
        cmy = __shfl(vy, 0) * (1.f / NPART);
    }

    // ---- C2. per-i epilogue (4 threads = lanes 0..3 of wave 0) ----
    if (tid < IPB) {
        const int g2 = blockIdx.x * IPB + tid;
        const float2 p = pos[g2];
        const float2 u = ori[g2];
        const float nrv = res[0][tid], sxv = res[1][tid], syv = res[2][tid];
        const float osx = res[3][tid], osy = res[4][tid];

        const float inv = 1.f / fmaxf(nrv, 1.f);
        const float sg  = (nrv > 0.f) ? 1.f : 0.f;
        const float Sx = sxv * inv - p.x * sg;
        const float Sy = syv * inv - p.y * sg;
        const float dxv = -Sx, dyv = -Sy;        // d = -S

        const float Psx = cmx - p.x;
        const float Psy = cmy - p.y;

        float sd, cd;
        sincosf(delv, &sd, &cd);
        const float Lx = Psx * cd - Psy * sd;    // Ps * exp(+i*Delta)
        const float Ly = Psx * sd + Psy * cd;
        const float Rx = Psx * cd + Psy * sd;    // Ps * exp(-i*Delta)
        const float Ry = Psy * cd - Psx * sd;

        const float no  = fmaxf(sqrtf(osx * osx + osy * osy + 1e-30f), EPSF);
        const float nl  = fmaxf(sqrtf(Lx * Lx + Ly * Ly + 1e-30f), EPSF);
        const float nrr = fmaxf(sqrtf(Rx * Rx + Ry * Ry + 1e-30f), EPSF);
        const float csl = (Lx * osx + Ly * osy) / (nl * no);
        const float csr = (Rx * osx + Ry * osy) / (nrr * no);
        const bool left = (csl >= csr);
        const float bx = left ? Lx : Rx;
        const float by = left ? Ly : Ry;

        float cx, cy;
        if (dxv != 0.f || dyv != 0.f)    { cx = dxv; cy = dyv; }
        else if (bx != 0.f || by != 0.f) { cx = bx;  cy = by;  }
        else                             { cx = 1.f; cy = 0.f; }

        const float dt_ = cx * u.x + cy * u.y;
        const float cr_ = cy * u.x - cx * u.y;
        const float sin_t = cr_ / sqrtf(dt_ * dt_ + cr_ * cr_);

        const float ang = C_ROT * sin_t + (rn_early * C_RN1) * C_SQDT;
        float sa, ca;
        sincosf(ang, &sa, &ca);
        out[1 * NPART + g2] = make_float2(u.x * ca - u.y * sa,
                                          u.x * sa + u.y * ca);
        out[2 * NPART + g2] = make_float2(osx, osy);
        out[3 * NPART + g2] = make_float2(Lx, Ly);
        out[4 * NPART + g2] = make_float2(Rx, Ry);
    }

    // ---- D2. three local JACOBI passes over S (nS <= 256 == NTHR) ----
    for (int pass = 0; pass < 3; ++pass) {
        float px = 0.f, py = 0.f, ax = 0.f, ay = 0.f;
        const bool mv = (tid < nS);
        if (mv) { px = posS[tid].x; py = posS[tid].y; }
        int b = 0;
        for (; b + 4 <= nS; b += 4) {
            const float4 w0 = posS4[(b >> 1)];
            const float4 w1 = posS4[(b >> 1) + 1];
            const float bxs[4] = {w0.x, w0.z, w1.x, w1.z};
            const float bys[4] = {w0.y, w0.w, w1.y, w1.w};
            #pragma unroll
            for (int s = 0; s < 4; ++s) {
                if (mv) {
                    const float dx = bxs[s] - px, dy = bys[s] - py;
                    const float r2 = fmaf(dx, dx, dy * dy);
                    if (r2 <= TWORC2 && r2 > 0.f) {
                        const float ab = sqrtf(r2);
                        const float sc = (C21RC - ab) * 0.5f / ab;
                        ax = fmaf(dx, sc, ax);
                        ay = fmaf(dy, sc, ay);
                    }
                }
            }
        }
        for (; b < nS; ++b) {
            const float2 pb = posS[b];
            if (mv) {
                const float dx = pb.x - px, dy = pb.y - py;
                const float r2 = fmaf(dx, dx, dy * dy);
                if (r2 <= TWORC2 && r2 > 0.f) {
                    const float ab = sqrtf(r2);
                    const float sc = (C21RC - ab) * 0.5f / ab;
                    ax = fmaf(dx, sc, ax);
                    ay = fmaf(dy, sc, ay);
                }
            }
        }
        __syncthreads();                  // all reads done (Jacobi)
        if (mv) posS[tid] = make_float2(px - ax, py - ay);
        __syncthreads();
    }
    // ---- section 0: own 4 i's are slots 0..3 of S ----
    if (tid < IPB)
        out[0 * NPART + blockIdx.x * IPB + tid] = posS[tid];
}

extern "C" void kernel_launch(void* const* d_in, const int* in_sizes, int n_in,
                              void* d_out, int out_size, void* d_ws, size_t ws_size,
                              hipStream_t stream) {
    const float2* pos = (const float2*)d_in[0];
    const float2* ori = (const float2*)d_in[1];
    const float*  del = (const float*)d_in[2];
    const float*  rn  = (const float*)d_in[3];
    const float2* tn  = (const float2*)d_in[4];
    float2* o2 = (float2*)d_out;          // [5][N] float2
    (void)d_ws; (void)ws_size;

    fused_all<<<dim3(NBLK), dim3(NTHR), 0, stream>>>(pos, ori, del, rn, tn, o2);
}